// Round 10
// baseline (219.577 us; speedup 1.0000x reference)
//
#include <hip/hip_runtime.h>
#include <hip/hip_bf16.h>

typedef __attribute__((ext_vector_type(8))) short short8;
typedef __attribute__((ext_vector_type(4))) float f32x4;
typedef __attribute__((ext_vector_type(4))) int i32x4;
typedef unsigned short u16;
typedef unsigned int u32;
typedef __attribute__((ext_vector_type(8))) unsigned short u16x8;
typedef __attribute__((ext_vector_type(4))) u32 u32x4;

#define XN 16
#define XC 64
#define XH 256
#define XW 256
#define XO 64
#define CH_STRIDE (XH * XW)   // 65536

// ---- i8 path ws layout (bytes) ----
#define QX_OFF    0                         // i8[16*256*256*64] = 67,108,864 (pixel-major NHWC)
#define INVS_OFF  67108864                  // f32[1048576] = 4,194,304
#define WBUF_OFF  71303168                  // i8[36864]
#define PART_OFF  71340032                  // f32[64]
#define WM_OFF    71340288                  // f32[1]
#define WS_NEED   71340544

// raw-asm loads: issue with no compiler-inserted waits; "memory" clobber keeps
// compiler stores from migrating across them (vmcnt counting must stay exact).
__device__ __forceinline__ i32x4 gload16(const void* p) {
    i32x4 r;
    asm volatile("global_load_dwordx4 %0, %1, off" : "=v"(r) : "v"(p) : "memory");
    return r;
}
__device__ __forceinline__ float gload4(const void* p) {
    float r;
    asm volatile("global_load_dword %0, %1, off" : "=v"(r) : "v"(p) : "memory");
    return r;
}

// ---------------------------------------------------------------------------
// Weight quant stage 1: deterministic partial |w| sums (64 blocks x 576 elems).
// ---------------------------------------------------------------------------
__global__ __launch_bounds__(256) void wq_reduce(const float* __restrict__ w,
                                                 float* __restrict__ partials) {
    __shared__ float red[4];
    const int tid = threadIdx.x;
    const int base = blockIdx.x * 576;       // 36864 / 64
    float s = 0.f;
    for (int i = tid; i < 576; i += 256) s += fabsf(w[base + i]);
    #pragma unroll
    for (int off = 32; off > 0; off >>= 1) s += __shfl_down(s, off, 64);
    if ((tid & 63) == 0) red[tid >> 6] = s;
    __syncthreads();
    if (tid == 0) partials[blockIdx.x] = red[0] + red[1] + red[2] + red[3];
}

// ---------------------------------------------------------------------------
// Weight quant stage 2: ternarize to i8 in MFMA A-fragment layout (144 blocks).
//   idx = ((t*4 + m)*64 + l)*16 + j
//   holds tern[o = m*16 + (l&15)][i = (l>>4)*16 + j]  for tap t
// ---------------------------------------------------------------------------
__global__ __launch_bounds__(256) void wq_tern_i8(const float* __restrict__ w,
                                                  const float* __restrict__ partials,
                                                  float* __restrict__ wm_out,
                                                  signed char* __restrict__ wbuf) {
    __shared__ float wm_sh;
    const int tid = threadIdx.x;
    if (tid == 0) {
        float tot = 0.f;
        #pragma unroll
        for (int i = 0; i < 64; ++i) tot += partials[i];   // fixed order: deterministic
        float wm = fmaxf(tot / (float)(XO * XC * 9), 1e-5f);
        wm_sh = wm;
        if (blockIdx.x == 0) wm_out[0] = wm;
    }
    __syncthreads();
    const float wscale = 1.0f / wm_sh;

    const int idx = blockIdx.x * 256 + tid;  // < 36864
    const int j = idx & 15;
    const int l = (idx >> 4) & 63;
    const int m = (idx >> 10) & 3;
    const int t = idx >> 12;                 // 0..8
    const int o = m * 16 + (l & 15);
    const int i = (l >> 4) * 16 + j;
    const int kh = t / 3, kw = t % 3;
    const float wv = w[((o * XC + i) * 3 + kh) * 3 + kw];
    const float tern = fminf(fmaxf(rintf(wv * wscale), -1.f), 1.f);
    wbuf[idx] = (signed char)(int)tern;
}

// ---------------------------------------------------------------------------
// Activation quant: one block per (n,h) row. qx = i8, pixel-major (64 B/px,
// channels contiguous). invs = amax/127 per pixel.
// ---------------------------------------------------------------------------
__global__ __launch_bounds__(256) void aq_i8(const float* __restrict__ x,
                                             signed char* __restrict__ qx,
                                             float* __restrict__ invs) {
    const int tid = threadIdx.x;
    const int b = blockIdx.x;            // 4096 = 16*256
    const int n = b >> 8;

    const float* px = x + ((size_t)n << 22) + ((size_t)(b & 255) << 8) + tid;
    float vals[64];
    float amax = 0.f;
    #pragma unroll
    for (int c = 0; c < 64; ++c) {
        const float v = px[(size_t)c << 16];
        vals[c] = v;
        amax = fmaxf(amax, fabsf(v));
    }
    const float am = fmaxf(amax, 1e-5f);
    const float scale = 127.0f / am;
    invs[((size_t)b << 8) + tid] = am * (1.0f / 127.0f);

    u32 words[16];
    #pragma unroll
    for (int wk = 0; wk < 16; ++wk) {
        u32 acc = 0;
        #pragma unroll
        for (int bb = 0; bb < 4; ++bb) {
            const float q = fminf(fmaxf(rintf(vals[wk * 4 + bb] * scale), -128.f), 127.f);
            acc |= ((u32)((int)q) & 255u) << (bb * 8);
        }
        words[wk] = acc;
    }
    u32* dst = (u32*)(qx + ((((size_t)b << 8) + tid) << 6));
    #pragma unroll
    for (int i = 0; i < 4; ++i) {
        *reinterpret_cast<u32x4*>(dst + i * 4) =
            (u32x4){words[i * 4], words[i * 4 + 1], words[i * 4 + 2], words[i * 4 + 3]};
    }
}

// ---------------------------------------------------------------------------
// Conv v7: software-pipelined. 1024 blocks x 8 iterations; wave = 1 output row
// x 32 px x 64 oc per iteration (block = 4 rows, slab = 32 rows over 8 iters).
// Per iter: issue next tile's 21 loads (18 x dwordx4 B-frags + 3 x dword IV
// row-loads, expanded to 18 IVs via __shfl) -> s_waitcnt vmcnt(29) (= 21 next
// loads + 8 prior NT stores; counted, never 0 in steady state) ->
// sched_barrier(0) -> 72 MFMA + dequant from the OTHER buffer -> full-line NT
// stores. A-fragment table staged to LDS once (its reads are lgkmcnt -> they
// don't perturb the vmcnt pipeline). BA/BB statically named (no dyn indexing).
// ---------------------------------------------------------------------------
#define PREFETCH(Bb, IVr, ITER) {                                              \
    const int gh_ = slab * 32 + (ITER) * 4 + wv;                               \
    const signed char* qr0_ = qn + ((size_t)max(gh_ - 1, 0) << 14);            \
    const signed char* qr1_ = qn + ((size_t)gh_ << 14);                        \
    const signed char* qr2_ = qn + ((size_t)min(gh_ + 1, XH - 1) << 14);       \
    IVr[0] = gload4(in + (max(gh_ - 1, 0) << 8) + ivcol);                      \
    IVr[1] = gload4(in + (gh_ << 8) + ivcol);                                  \
    IVr[2] = gload4(in + (min(gh_ + 1, XH - 1) << 8) + ivcol);                 \
    _Pragma("unroll")                                                          \
    for (int dw_ = 0; dw_ < 3; ++dw_) {                                        \
        Bb[0 + dw_ * 2 + 0] = gload16(qr0_ + (gwc[0][dw_] << 6) + (lg << 4));  \
        Bb[0 + dw_ * 2 + 1] = gload16(qr0_ + (gwc[1][dw_] << 6) + (lg << 4));  \
        Bb[6 + dw_ * 2 + 0] = gload16(qr1_ + (gwc[0][dw_] << 6) + (lg << 4));  \
        Bb[6 + dw_ * 2 + 1] = gload16(qr1_ + (gwc[1][dw_] << 6) + (lg << 4));  \
        Bb[12 + dw_ * 2 + 0] = gload16(qr2_ + (gwc[0][dw_] << 6) + (lg << 4)); \
        Bb[12 + dw_ * 2 + 1] = gload16(qr2_ + (gwc[1][dw_] << 6) + (lg << 4)); \
    }                                                                          \
}

#define COMPUTE(Bb, IVr, ITER) {                                               \
    const int gh_ = slab * 32 + (ITER) * 4 + wv;                               \
    const bool rok0_ = (gh_ > 0), rok2_ = (gh_ < XH - 1);                      \
    f32x4 acc_[4][2];                                                          \
    _Pragma("unroll")                                                          \
    for (int m_ = 0; m_ < 4; ++m_) {                                           \
        acc_[m_][0] = (f32x4){0.f, 0.f, 0.f, 0.f};                             \
        acc_[m_][1] = (f32x4){0.f, 0.f, 0.f, 0.f};                             \
    }                                                                          \
    _Pragma("unroll")                                                          \
    for (int dh_ = 0; dh_ < 3; ++dh_) {                                        \
        const bool rok_ = (dh_ == 0) ? rok0_ : ((dh_ == 2) ? rok2_ : true);    \
        float iv_[3][2];                                                       \
        _Pragma("unroll")                                                      \
        for (int dw_ = 0; dw_ < 3; ++dw_)                                      \
            _Pragma("unroll")                                                  \
            for (int nt_ = 0; nt_ < 2; ++nt_) {                                \
                const float s_ = __shfl(IVr[dh_], nt_ * 16 + l15 + dw_, 64);   \
                iv_[dw_][nt_] = (rok_ & cok[nt_][dw_]) ? s_ : 0.f;             \
            }                                                                  \
        _Pragma("unroll")                                                      \
        for (int dw_ = 0; dw_ < 3; ++dw_) {                                    \
            const int t_ = dh_ * 3 + dw_;                                      \
            _Pragma("unroll")                                                  \
            for (int m_ = 0; m_ < 4; ++m_) {                                   \
                const i32x4 af_ = *reinterpret_cast<const i32x4*>(             \
                    albs + (((t_ << 2) + m_) << 10) + (lane << 4));            \
                _Pragma("unroll")                                              \
                for (int nt_ = 0; nt_ < 2; ++nt_) {                            \
                    i32x4 tap_ = __builtin_amdgcn_mfma_i32_16x16x64_i8(        \
                        af_, Bb[dh_ * 6 + dw_ * 2 + nt_], (i32x4){0,0,0,0},    \
                        0, 0, 0);                                              \
                    f32x4 tf_;                                                 \
                    tf_[0] = (float)tap_[0]; tf_[1] = (float)tap_[1];          \
                    tf_[2] = (float)tap_[2]; tf_[3] = (float)tap_[3];          \
                    acc_[m_][nt_] += tf_ * iv_[dw_][nt_];                      \
                }                                                              \
            }                                                                  \
        }                                                                      \
    }                                                                          \
    _Pragma("unroll")                                                          \
    for (int m_ = 0; m_ < 4; ++m_)                                             \
        _Pragma("unroll")                                                      \
        for (int nt_ = 0; nt_ < 2; ++nt_)                                      \
            _Pragma("unroll")                                                  \
            for (int r_ = 0; r_ < 4; ++r_) {                                   \
                const int o_ = (m_ << 4) + (lg << 2) + r_;                     \
                eplds[wv][o_][(nt_ << 4) + l15] =                              \
                    fmaf(acc_[m_][nt_][r_], wm, bias_v[m_][r_]);               \
            }                                                                  \
    _Pragma("unroll")                                                          \
    for (int j_ = 0; j_ < 8; ++j_) {                                           \
        const int o_ = (j_ << 3) + (lane >> 3);                                \
        const int px0_ = (lane & 7) << 2;                                      \
        const f32x4 v_ = *reinterpret_cast<const f32x4*>(&eplds[wv][o_][px0_]);\
        float* dst_ = out + ((((size_t)n << 6) + o_) << 16) + (gh_ << 8)       \
                      + w0 + px0_;                                             \
        __builtin_nontemporal_store(v_, reinterpret_cast<f32x4*>(dst_));       \
    }                                                                          \
}

__global__ __launch_bounds__(256, 2) void conv_i8p(const signed char* __restrict__ qx,
                                                   const float* __restrict__ invs,
                                                   const signed char* __restrict__ wbuf,
                                                   const float* __restrict__ wm_ptr,
                                                   const float* __restrict__ bias,
                                                   float* __restrict__ out) {
    __shared__ __align__(16) signed char albs[36864];   // A-frag table (LDS copy)
    __shared__ float eplds[4][64][36];                  // 36,864 B epilogue buf

    const int tid = threadIdx.x;
    // bijective XCD swizzle: 1024 blocks % 8 == 0
    const int bid  = (blockIdx.x & 7) * 128 + (blockIdx.x >> 3);
    const int n    = bid >> 6;            // 16 images
    const int slab = (bid >> 3) & 7;      // 8 slabs of 32 rows
    const int w0   = (bid & 7) << 5;      // 8 col groups of 32 px
    const int wv   = tid >> 6;
    const int lane = tid & 63;
    const int l15 = lane & 15;
    const int lg  = lane >> 4;

    // ---- stage A-fragment table to LDS (once per block) ----
    {
        const i32x4* src = reinterpret_cast<const i32x4*>(wbuf);
        i32x4* dst = reinterpret_cast<i32x4*>(albs);
        #pragma unroll
        for (int i = 0; i < 9; ++i) dst[tid + i * 256] = src[tid + i * 256];
    }
    __syncthreads();   // drains vmcnt too -> clean slate for counted waits

    const signed char* qn = qx + ((size_t)n << 22);
    const float*       in = invs + ((size_t)n << 16);

    // iteration-invariant per-lane columns
    int gwc[2][3]; bool cok[2][3];
    #pragma unroll
    for (int nt = 0; nt < 2; ++nt)
        #pragma unroll
        for (int dw = 0; dw < 3; ++dw) {
            const int gw = w0 + nt * 16 + l15 + dw - 1;
            cok[nt][dw] = (gw >= 0) & (gw < XW);
            gwc[nt][dw] = min(max(gw, 0), XW - 1);
        }
    const int ivcol = min(max(w0 + lane - 1, 0), XW - 1);

    const float wm = wm_ptr[0];
    float bias_v[4][4];
    #pragma unroll
    for (int m = 0; m < 4; ++m)
        #pragma unroll
        for (int r = 0; r < 4; ++r)
            bias_v[m][r] = bias[(m << 4) + (lg << 2) + r];

    i32x4 BA[18], BB[18];
    float IVA[3], IVB[3];

    // prologue + peeled iteration 0
    PREFETCH(BA, IVA, 0);
    PREFETCH(BB, IVB, 1);
    asm volatile("s_waitcnt vmcnt(21)" ::: "memory");   // BA done (21 newer = BB)
    __builtin_amdgcn_sched_barrier(0);
    COMPUTE(BA, IVA, 0);

    #pragma unroll 1
    for (int ith = 0; ith < 3; ++ith) {
        const int ito = 2 * ith + 1;
        PREFETCH(BA, IVA, ito + 1);
        asm volatile("s_waitcnt vmcnt(29)" ::: "memory");  // 21 loads + 8 stores newer
        __builtin_amdgcn_sched_barrier(0);
        COMPUTE(BB, IVB, ito);
        PREFETCH(BB, IVB, ito + 2);
        asm volatile("s_waitcnt vmcnt(29)" ::: "memory");
        __builtin_amdgcn_sched_barrier(0);
        COMPUTE(BA, IVA, ito + 1);
    }

    // tail: iteration 7 (no prefetch; 8 stores of iter 6 are the only newer ops)
    asm volatile("s_waitcnt vmcnt(8)" ::: "memory");
    __builtin_amdgcn_sched_barrier(0);
    COMPUTE(BB, IVB, 7);
}

// ===========================================================================
// Fallback (round-1, verified): fused bf16 kernel pair, needs ~74 KB of ws.
// ===========================================================================
#define HALO_W 34
#define NPIX 340

__global__ __launch_bounds__(256) void wq_kernel(const float* __restrict__ w,
                                                 float* __restrict__ wm_out,
                                                 u16* __restrict__ wbuf) {
    __shared__ float red[4];
    __shared__ float wm_sh;
    const int tid = threadIdx.x;

    float s = 0.f;
    for (int i = tid; i < XO * XC * 9; i += 256) s += fabsf(w[i]);
    #pragma unroll
    for (int off = 32; off > 0; off >>= 1) s += __shfl_down(s, off, 64);
    if ((tid & 63) == 0) red[tid >> 6] = s;
    __syncthreads();
    if (tid == 0) {
        float tot = red[0] + red[1] + red[2] + red[3];
        float wm = fmaxf(tot / (float)(XO * XC * 9), 1e-5f);
        wm_out[0] = wm;
        wm_sh = wm;
    }
    __syncthreads();
    const float wscale = 1.0f / wm_sh;

    for (int idx = tid; idx < XO * XC * 9; idx += 256) {
        const int j = idx & 7;
        const int l = (idx >> 3) & 63;
        const int c = (idx >> 9) & 1;
        const int m = (idx >> 10) & 3;
        const int t = idx >> 12;
        const int o = m * 16 + (l & 15);
        const int i = c * 32 + (l >> 4) * 8 + j;
        const int kh = t / 3, kw = t % 3;
        const float wv = w[((o * XC + i) * 3 + kh) * 3 + kw];
        const float tern = fminf(fmaxf(rintf(wv * wscale), -1.f), 1.f);
        wbuf[idx] = (u16)(__float_as_uint(tern) >> 16);
    }
}

__global__ __launch_bounds__(256) void conv_kernel(const float* __restrict__ x,
                                                   const u16* __restrict__ wbuf,
                                                   const float* __restrict__ wm_ptr,
                                                   const float* __restrict__ bias,
                                                   float* __restrict__ out) {
    __shared__ __align__(16) u16 q_lds[NPIX * 64];
    __shared__ float invs_lds[NPIX];
    __shared__ float bias_lds[XO];

    const int tid = threadIdx.x;
    const int bid = blockIdx.x;
    const int n   = bid >> 8;
    const int rem = bid & 255;
    const int h0  = (rem >> 3) << 3;
    const int w0  = (rem & 7) << 5;

    if (tid < XO) bias_lds[tid] = bias[tid];

    #pragma unroll 1
    for (int p = tid; p < NPIX; p += 256) {
        const int hr = p / HALO_W;
        const int cl = p - hr * HALO_W;
        const int gh = h0 + hr - 1;
        const int gw = w0 + cl - 1;
        const bool ok = (gh >= 0) & (gh < XH) & (gw >= 0) & (gw < XW);

        float vals[64];
        float amax = 0.f;
        if (ok) {
            const float* px = x + (size_t)n * (XC * CH_STRIDE) + (size_t)gh * XW + gw;
            #pragma unroll
            for (int c = 0; c < 64; ++c) {
                const float v = px[(size_t)c * CH_STRIDE];
                vals[c] = v;
                amax = fmaxf(amax, fabsf(v));
            }
        } else {
            #pragma unroll
            for (int c = 0; c < 64; ++c) vals[c] = 0.f;
        }
        const float am    = fmaxf(amax, 1e-5f);
        const float scale = 127.0f / am;
        invs_lds[p] = ok ? (1.0f / scale) : 0.0f;

        const int sw = (p & 7) << 3;
        #pragma unroll
        for (int cb = 0; cb < 8; ++cb) {
            u16x8 pk;
            #pragma unroll
            for (int j = 0; j < 8; ++j) {
                const float q = fminf(fmaxf(rintf(vals[cb * 8 + j] * scale), -128.f), 127.f);
                pk[j] = (u16)(__float_as_uint(q) >> 16);
            }
            *reinterpret_cast<u16x8*>(&q_lds[p * 64 + ((cb * 8) ^ sw)]) = pk;
        }
    }
    __syncthreads();

    const int lane = tid & 63;
    const int wv   = tid >> 6;
    const int l15  = lane & 15;
    const int lg   = lane >> 4;

    f32x4 acc[4][4];
    #pragma unroll
    for (int m = 0; m < 4; ++m)
        #pragma unroll
        for (int nt = 0; nt < 4; ++nt) acc[m][nt] = (f32x4){0.f, 0.f, 0.f, 0.f};

    const float wm = wm_ptr[0];

    #pragma unroll
    for (int t = 0; t < 9; ++t) {
        const int dh = t / 3, dw = t % 3;

        short8 afr[4][2];
        #pragma unroll
        for (int m = 0; m < 4; ++m)
            #pragma unroll
            for (int c = 0; c < 2; ++c)
                afr[m][c] = *reinterpret_cast<const short8*>(
                    wbuf + ((((t * 4 + m) * 2 + c) * 64 + lane) * 8));

        #pragma unroll
        for (int nt = 0; nt < 4; ++nt) {
            const int rl  = 2 * wv + (nt >> 1);
            const int pix = (rl + dh) * HALO_W + (nt & 1) * 16 + l15 + dw;
            const int sw  = (pix & 7) << 3;
            const u16* qp = &q_lds[pix * 64];
            const short8 b0 = *reinterpret_cast<const short8*>(qp + ((lg * 8) ^ sw));
            const short8 b1 = *reinterpret_cast<const short8*>(qp + ((32 + lg * 8) ^ sw));
            const float  iv = invs_lds[pix];
            #pragma unroll
            for (int m = 0; m < 4; ++m) {
                f32x4 tap = (f32x4){0.f, 0.f, 0.f, 0.f};
                tap = __builtin_amdgcn_mfma_f32_16x16x32_bf16(afr[m][0], b0, tap, 0, 0, 0);
                tap = __builtin_amdgcn_mfma_f32_16x16x32_bf16(afr[m][1], b1, tap, 0, 0, 0);
                acc[m][nt] += tap * iv;
            }
        }
    }

    #pragma unroll
    for (int m = 0; m < 4; ++m) {
        #pragma unroll
        for (int nt = 0; nt < 4; ++nt) {
            const int rl = 2 * wv + (nt >> 1);
            const int gh = h0 + rl;
            const int gw = w0 + (nt & 1) * 16 + l15;
            #pragma unroll
            for (int r = 0; r < 4; ++r) {
                const int o = m * 16 + lg * 4 + r;
                const float v = wm * acc[m][nt][r] + bias_lds[o];
                out[(((size_t)n * XO + o) * XH + gh) * XW + gw] = v;
            }
        }
    }
}

extern "C" void kernel_launch(void* const* d_in, const int* in_sizes, int n_in,
                              void* d_out, int out_size, void* d_ws, size_t ws_size,
                              hipStream_t stream) {
    const float* x    = (const float*)d_in[0];
    const float* w    = (const float*)d_in[1];
    const float* bias = (const float*)d_in[2];
    float* out = (float*)d_out;

    if (ws_size >= (size_t)WS_NEED) {
        signed char* qx       = (signed char*)d_ws;
        float*       invsb    = (float*)((char*)d_ws + INVS_OFF);
        signed char* wbuf     = (signed char*)((char*)d_ws + WBUF_OFF);
        float*       partials = (float*)((char*)d_ws + PART_OFF);
        float*       wm       = (float*)((char*)d_ws + WM_OFF);

        wq_reduce<<<64, 256, 0, stream>>>(w, partials);
        wq_tern_i8<<<144, 256, 0, stream>>>(w, partials, wm, wbuf);
        aq_i8<<<XN * 256, 256, 0, stream>>>(x, qx, invsb);
        conv_i8p<<<1024, 256, 0, stream>>>(qx, invsb, wbuf, wm, bias, out);
    } else {
        float* wsf  = (float*)d_ws;
        u16*   wbuf = (u16*)((char*)d_ws + 64);
        wq_kernel<<<1, 256, 0, stream>>>(w, wsf, wbuf);
        conv_kernel<<<XN * 256, 256, 0, stream>>>(x, wbuf, wsf, bias, out);
    }
}

// Round 11
// 177.371 us; speedup vs baseline: 1.2380x; 1.2380x over previous
//
#include <hip/hip_runtime.h>
#include <hip/hip_bf16.h>

typedef __attribute__((ext_vector_type(8))) short short8;
typedef __attribute__((ext_vector_type(4))) float f32x4;
typedef __attribute__((ext_vector_type(4))) int i32x4;
typedef unsigned short u16;
typedef unsigned int u32;
typedef __attribute__((ext_vector_type(8))) unsigned short u16x8;
typedef __attribute__((ext_vector_type(4))) u32 u32x4;

#define XN 16
#define XC 64
#define XH 256
#define XW 256
#define XO 64
#define CH_STRIDE (XH * XW)   // 65536

// ---- i8 path ws layout (bytes) ----
#define QX_OFF    0                         // i8[16*256*256*64] = 67,108,864 (pixel-major NHWC)
#define INVS_OFF  67108864                  // f32[1048576] = 4,194,304
#define WBUF_OFF  71303168                  // i8[36864]
#define PART_OFF  71340032                  // f32[64]
#define WM_OFF    71340288                  // f32[1]
#define WS_NEED   71340544

// raw-asm loads: issue back-to-back with no compiler-inserted waits.
__device__ __forceinline__ i32x4 gload16(const void* p) {
    i32x4 r;
    asm volatile("global_load_dwordx4 %0, %1, off" : "=v"(r) : "v"(p) : "memory");
    return r;
}
__device__ __forceinline__ float gload4(const void* p) {
    float r;
    asm volatile("global_load_dword %0, %1, off" : "=v"(r) : "v"(p) : "memory");
    return r;
}

// ---------------------------------------------------------------------------
// Weight quant stage 1: deterministic partial |w| sums (64 blocks x 576 elems).
// ---------------------------------------------------------------------------
__global__ __launch_bounds__(256) void wq_reduce(const float* __restrict__ w,
                                                 float* __restrict__ partials) {
    __shared__ float red[4];
    const int tid = threadIdx.x;
    const int base = blockIdx.x * 576;       // 36864 / 64
    float s = 0.f;
    for (int i = tid; i < 576; i += 256) s += fabsf(w[base + i]);
    #pragma unroll
    for (int off = 32; off > 0; off >>= 1) s += __shfl_down(s, off, 64);
    if ((tid & 63) == 0) red[tid >> 6] = s;
    __syncthreads();
    if (tid == 0) partials[blockIdx.x] = red[0] + red[1] + red[2] + red[3];
}

// ---------------------------------------------------------------------------
// Weight quant stage 2: ternarize to i8 in MFMA A-fragment layout (144 blocks).
//   idx = ((t*4 + m)*64 + l)*16 + j
//   holds tern[o = m*16 + (l&15)][i = (l>>4)*16 + j]  for tap t
// ---------------------------------------------------------------------------
__global__ __launch_bounds__(256) void wq_tern_i8(const float* __restrict__ w,
                                                  const float* __restrict__ partials,
                                                  float* __restrict__ wm_out,
                                                  signed char* __restrict__ wbuf) {
    __shared__ float wm_sh;
    const int tid = threadIdx.x;
    if (tid == 0) {
        float tot = 0.f;
        #pragma unroll
        for (int i = 0; i < 64; ++i) tot += partials[i];   // fixed order: deterministic
        float wm = fmaxf(tot / (float)(XO * XC * 9), 1e-5f);
        wm_sh = wm;
        if (blockIdx.x == 0) wm_out[0] = wm;
    }
    __syncthreads();
    const float wscale = 1.0f / wm_sh;

    const int idx = blockIdx.x * 256 + tid;  // < 36864
    const int j = idx & 15;
    const int l = (idx >> 4) & 63;
    const int m = (idx >> 10) & 3;
    const int t = idx >> 12;                 // 0..8
    const int o = m * 16 + (l & 15);
    const int i = (l >> 4) * 16 + j;
    const int kh = t / 3, kw = t % 3;
    const float wv = w[((o * XC + i) * 3 + kh) * 3 + kw];
    const float tern = fminf(fmaxf(rintf(wv * wscale), -1.f), 1.f);
    wbuf[idx] = (signed char)(int)tern;
}

// ---------------------------------------------------------------------------
// Activation quant: one block per (n,h) row. qx = i8, pixel-major (64 B/px,
// channels contiguous). invs = amax/127 per pixel.
// ---------------------------------------------------------------------------
__global__ __launch_bounds__(256) void aq_i8(const float* __restrict__ x,
                                             signed char* __restrict__ qx,
                                             float* __restrict__ invs) {
    const int tid = threadIdx.x;
    const int b = blockIdx.x;            // 4096 = 16*256
    const int n = b >> 8;

    const float* px = x + ((size_t)n << 22) + ((size_t)(b & 255) << 8) + tid;
    float vals[64];
    float amax = 0.f;
    #pragma unroll
    for (int c = 0; c < 64; ++c) {
        const float v = px[(size_t)c << 16];
        vals[c] = v;
        amax = fmaxf(amax, fabsf(v));
    }
    const float am = fmaxf(amax, 1e-5f);
    const float scale = 127.0f / am;
    invs[((size_t)b << 8) + tid] = am * (1.0f / 127.0f);

    u32 words[16];
    #pragma unroll
    for (int wk = 0; wk < 16; ++wk) {
        u32 acc = 0;
        #pragma unroll
        for (int bb = 0; bb < 4; ++bb) {
            const float q = fminf(fmaxf(rintf(vals[wk * 4 + bb] * scale), -128.f), 127.f);
            acc |= ((u32)((int)q) & 255u) << (bb * 8);
        }
        words[wk] = acc;
    }
    u32* dst = (u32*)(qx + ((((size_t)b << 8) + tid) << 6));
    #pragma unroll
    for (int i = 0; i < 4; ++i) {
        *reinterpret_cast<u32x4*>(dst + i * 4) =
            (u32x4){words[i * 4], words[i * 4 + 1], words[i * 4 + 2], words[i * 4 + 3]};
    }
}

// ---------------------------------------------------------------------------
// Conv v8: occupancy-first. Wave = 1 output row x 32 px x 64 oc; block = 4
// rows; grid 8192, XCD-swizzled. One batched asm load phase (18 dwordx4 B +
// 18 dword IV) -> single s_waitcnt vmcnt(0) -> sched_barrier(0) -> 72 MFMA +
// dequant -> LDS full-line epilogue (single-row buffer, 36,864 B total).
// __launch_bounds__(256,3): ~145 live VGPR fits the 168 cap, LDS 36.9 KB ->
// 3 blocks/CU (was 2) so load exposure of one block hides under compute of
// the others (m114 wave-level overlap).
// ---------------------------------------------------------------------------
__global__ __launch_bounds__(256, 3) void conv_i8(const signed char* __restrict__ qx,
                                                  const float* __restrict__ invs,
                                                  const signed char* __restrict__ wbuf,
                                                  const float* __restrict__ wm_ptr,
                                                  const float* __restrict__ bias,
                                                  float* __restrict__ out) {
    __shared__ float eplds[4][64][36];   // 36,864 B; per-wave private regions

    const int tid = threadIdx.x;
    // bijective XCD swizzle: 8192 blocks % 8 == 0
    const int bid = (blockIdx.x & 7) * 1024 + (blockIdx.x >> 3);
    const int n      = bid >> 9;           // 512 blocks/image
    const int rem    = bid & 511;
    const int rowgrp = rem >> 3;           // 0..63, 4 rows each
    const int w0     = (rem & 7) << 5;     // 0..224
    const int wv     = tid >> 6;
    const int gh     = (rowgrp << 2) + wv; // this wave's output row
    const int lane = tid & 63;
    const int l15 = lane & 15;
    const int lg  = lane >> 4;

    const signed char* qn = qx + ((size_t)n << 22);          // n * 256*256*64
    const float*       in = invs + ((size_t)n << 16);

    // per-lane clamped cols for nt in {0,1}, dw in {0,1,2}
    int gwc[2][3]; bool cok[2][3];
    #pragma unroll
    for (int nt = 0; nt < 2; ++nt)
        #pragma unroll
        for (int dw = 0; dw < 3; ++dw) {
            const int gw = w0 + nt * 16 + l15 + dw - 1;
            cok[nt][dw] = (gw >= 0) & (gw < XW);
            gwc[nt][dw] = min(max(gw, 0), XW - 1);
        }

    // ---- ONE batched load phase: 18 x dwordx4 + 18 x dword, single drain ----
    i32x4 B[3][3][2];
    float IVr[3][3][2];
    bool  rokv[3];
    #pragma unroll
    for (int dh = 0; dh < 3; ++dh) {
        const int ghi = gh + dh - 1;
        rokv[dh] = (ghi >= 0) & (ghi < XH);
        const int ghc = min(max(ghi, 0), XH - 1);
        const signed char* qrow = qn + ((size_t)ghc << 14);   // 256 px * 64 B
        const float*       irow = in + (ghc << 8);
        #pragma unroll
        for (int dw = 0; dw < 3; ++dw)
            #pragma unroll
            for (int nt = 0; nt < 2; ++nt) {
                const int c = gwc[nt][dw];
                B[dh][dw][nt]   = gload16(qrow + (c << 6) + (lg << 4));
                IVr[dh][dw][nt] = gload4(irow + c);
            }
    }
    asm volatile("s_waitcnt vmcnt(0)" ::: "memory");
    __builtin_amdgcn_sched_barrier(0);

    float IV[3][3][2];
    #pragma unroll
    for (int dh = 0; dh < 3; ++dh)
        #pragma unroll
        for (int dw = 0; dw < 3; ++dw)
            #pragma unroll
            for (int nt = 0; nt < 2; ++nt)
                IV[dh][dw][nt] = (rokv[dh] & cok[nt][dw]) ? IVr[dh][dw][nt] : 0.f;

    f32x4 acc[4][2];
    #pragma unroll
    for (int m = 0; m < 4; ++m) {
        acc[m][0] = (f32x4){0.f, 0.f, 0.f, 0.f};
        acc[m][1] = (f32x4){0.f, 0.f, 0.f, 0.f};
    }

    #pragma unroll
    for (int dh = 0; dh < 3; ++dh) {
        #pragma unroll
        for (int dw = 0; dw < 3; ++dw) {
            const int t = dh * 3 + dw;
            #pragma unroll
            for (int m = 0; m < 4; ++m) {
                const i32x4 af = *reinterpret_cast<const i32x4*>(
                    wbuf + (((t << 2) + m) << 10) + (lane << 4));
                #pragma unroll
                for (int nt = 0; nt < 2; ++nt) {
                    i32x4 tap = __builtin_amdgcn_mfma_i32_16x16x64_i8(
                        af, B[dh][dw][nt], (i32x4){0, 0, 0, 0}, 0, 0, 0);
                    f32x4 tf;
                    tf[0] = (float)tap[0]; tf[1] = (float)tap[1];
                    tf[2] = (float)tap[2]; tf[3] = (float)tap[3];
                    acc[m][nt] += tf * IV[dh][dw][nt];
                }
            }
        }
    }

    // ---- epilogue: acc -> LDS (wm+bias folded) -> full-128B-line NT stores ----
    const float wm = wm_ptr[0];
    #pragma unroll
    for (int m = 0; m < 4; ++m)
        #pragma unroll
        for (int nt = 0; nt < 2; ++nt)
            #pragma unroll
            for (int r = 0; r < 4; ++r) {
                const int o = (m << 4) + (lg << 2) + r;
                eplds[wv][o][(nt << 4) + l15] =
                    fmaf(acc[m][nt][r], wm, bias[o]);
            }

    // same-wave LDS readback; each 8-lane group covers one full 128-B line
    #pragma unroll
    for (int j = 0; j < 8; ++j) {
        const int o   = (j << 3) + (lane >> 3);
        const int px0 = (lane & 7) << 2;
        const f32x4 v = *reinterpret_cast<const f32x4*>(&eplds[wv][o][px0]);
        float* dst = out + ((((size_t)n << 6) + o) << 16) + (gh << 8) + w0 + px0;
        __builtin_nontemporal_store(v, reinterpret_cast<f32x4*>(dst));
    }
}

// ===========================================================================
// Fallback (round-1, verified): fused bf16 kernel pair, needs ~74 KB of ws.
// ===========================================================================
#define HALO_W 34
#define NPIX 340

__global__ __launch_bounds__(256) void wq_kernel(const float* __restrict__ w,
                                                 float* __restrict__ wm_out,
                                                 u16* __restrict__ wbuf) {
    __shared__ float red[4];
    __shared__ float wm_sh;
    const int tid = threadIdx.x;

    float s = 0.f;
    for (int i = tid; i < XO * XC * 9; i += 256) s += fabsf(w[i]);
    #pragma unroll
    for (int off = 32; off > 0; off >>= 1) s += __shfl_down(s, off, 64);
    if ((tid & 63) == 0) red[tid >> 6] = s;
    __syncthreads();
    if (tid == 0) {
        float tot = red[0] + red[1] + red[2] + red[3];
        float wm = fmaxf(tot / (float)(XO * XC * 9), 1e-5f);
        wm_out[0] = wm;
        wm_sh = wm;
    }
    __syncthreads();
    const float wscale = 1.0f / wm_sh;

    for (int idx = tid; idx < XO * XC * 9; idx += 256) {
        const int j = idx & 7;
        const int l = (idx >> 3) & 63;
        const int c = (idx >> 9) & 1;
        const int m = (idx >> 10) & 3;
        const int t = idx >> 12;
        const int o = m * 16 + (l & 15);
        const int i = c * 32 + (l >> 4) * 8 + j;
        const int kh = t / 3, kw = t % 3;
        const float wv = w[((o * XC + i) * 3 + kh) * 3 + kw];
        const float tern = fminf(fmaxf(rintf(wv * wscale), -1.f), 1.f);
        wbuf[idx] = (u16)(__float_as_uint(tern) >> 16);
    }
}

__global__ __launch_bounds__(256) void conv_kernel(const float* __restrict__ x,
                                                   const u16* __restrict__ wbuf,
                                                   const float* __restrict__ wm_ptr,
                                                   const float* __restrict__ bias,
                                                   float* __restrict__ out) {
    __shared__ __align__(16) u16 q_lds[NPIX * 64];
    __shared__ float invs_lds[NPIX];
    __shared__ float bias_lds[XO];

    const int tid = threadIdx.x;
    const int bid = blockIdx.x;
    const int n   = bid >> 8;
    const int rem = bid & 255;
    const int h0  = (rem >> 3) << 3;
    const int w0  = (rem & 7) << 5;

    if (tid < XO) bias_lds[tid] = bias[tid];

    #pragma unroll 1
    for (int p = tid; p < NPIX; p += 256) {
        const int hr = p / HALO_W;
        const int cl = p - hr * HALO_W;
        const int gh = h0 + hr - 1;
        const int gw = w0 + cl - 1;
        const bool ok = (gh >= 0) & (gh < XH) & (gw >= 0) & (gw < XW);

        float vals[64];
        float amax = 0.f;
        if (ok) {
            const float* px = x + (size_t)n * (XC * CH_STRIDE) + (size_t)gh * XW + gw;
            #pragma unroll
            for (int c = 0; c < 64; ++c) {
                const float v = px[(size_t)c * CH_STRIDE];
                vals[c] = v;
                amax = fmaxf(amax, fabsf(v));
            }
        } else {
            #pragma unroll
            for (int c = 0; c < 64; ++c) vals[c] = 0.f;
        }
        const float am    = fmaxf(amax, 1e-5f);
        const float scale = 127.0f / am;
        invs_lds[p] = ok ? (1.0f / scale) : 0.0f;

        const int sw = (p & 7) << 3;
        #pragma unroll
        for (int cb = 0; cb < 8; ++cb) {
            u16x8 pk;
            #pragma unroll
            for (int j = 0; j < 8; ++j) {
                const float q = fminf(fmaxf(rintf(vals[cb * 8 + j] * scale), -128.f), 127.f);
                pk[j] = (u16)(__float_as_uint(q) >> 16);
            }
            *reinterpret_cast<u16x8*>(&q_lds[p * 64 + ((cb * 8) ^ sw)]) = pk;
        }
    }
    __syncthreads();

    const int lane = tid & 63;
    const int wv   = tid >> 6;
    const int l15  = lane & 15;
    const int lg   = lane >> 4;

    f32x4 acc[4][4];
    #pragma unroll
    for (int m = 0; m < 4; ++m)
        #pragma unroll
        for (int nt = 0; nt < 4; ++nt) acc[m][nt] = (f32x4){0.f, 0.f, 0.f, 0.f};

    const float wm = wm_ptr[0];

    #pragma unroll
    for (int t = 0; t < 9; ++t) {
        const int dh = t / 3, dw = t % 3;

        short8 afr[4][2];
        #pragma unroll
        for (int m = 0; m < 4; ++m)
            #pragma unroll
            for (int c = 0; c < 2; ++c)
                afr[m][c] = *reinterpret_cast<const short8*>(
                    wbuf + ((((t * 4 + m) * 2 + c) * 64 + lane) * 8));

        #pragma unroll
        for (int nt = 0; nt < 4; ++nt) {
            const int rl  = 2 * wv + (nt >> 1);
            const int pix = (rl + dh) * HALO_W + (nt & 1) * 16 + l15 + dw;
            const int sw  = (pix & 7) << 3;
            const u16* qp = &q_lds[pix * 64];
            const short8 b0 = *reinterpret_cast<const short8*>(qp + ((lg * 8) ^ sw));
            const short8 b1 = *reinterpret_cast<const short8*>(qp + ((32 + lg * 8) ^ sw));
            const float  iv = invs_lds[pix];
            #pragma unroll
            for (int m = 0; m < 4; ++m) {
                f32x4 tap = (f32x4){0.f, 0.f, 0.f, 0.f};
                tap = __builtin_amdgcn_mfma_f32_16x16x32_bf16(afr[m][0], b0, tap, 0, 0, 0);
                tap = __builtin_amdgcn_mfma_f32_16x16x32_bf16(afr[m][1], b1, tap, 0, 0, 0);
                acc[m][nt] += tap * iv;
            }
        }
    }

    #pragma unroll
    for (int m = 0; m < 4; ++m) {
        #pragma unroll
        for (int nt = 0; nt < 4; ++nt) {
            const int rl = 2 * wv + (nt >> 1);
            const int gh = h0 + rl;
            const int gw = w0 + (nt & 1) * 16 + l15;
            #pragma unroll
            for (int r = 0; r < 4; ++r) {
                const int o = m * 16 + lg * 4 + r;
                const float v = wm * acc[m][nt][r] + bias_lds[o];
                out[(((size_t)n * XO + o) * XH + gh) * XW + gw] = v;
            }
        }
    }
}

extern "C" void kernel_launch(void* const* d_in, const int* in_sizes, int n_in,
                              void* d_out, int out_size, void* d_ws, size_t ws_size,
                              hipStream_t stream) {
    const float* x    = (const float*)d_in[0];
    const float* w    = (const float*)d_in[1];
    const float* bias = (const float*)d_in[2];
    float* out = (float*)d_out;

    if (ws_size >= (size_t)WS_NEED) {
        signed char* qx       = (signed char*)d_ws;
        float*       invsb    = (float*)((char*)d_ws + INVS_OFF);
        signed char* wbuf     = (signed char*)((char*)d_ws + WBUF_OFF);
        float*       partials = (float*)((char*)d_ws + PART_OFF);
        float*       wm       = (float*)((char*)d_ws + WM_OFF);

        wq_reduce<<<64, 256, 0, stream>>>(w, partials);
        wq_tern_i8<<<144, 256, 0, stream>>>(w, partials, wm, wbuf);
        aq_i8<<<XN * 256, 256, 0, stream>>>(x, qx, invsb);
        conv_i8<<<XN * 512, 256, 0, stream>>>(qx, invsb, wbuf, wm, bias, out);
    } else {
        float* wsf  = (float*)d_ws;
        u16*   wbuf = (u16*)((char*)d_ws + 64);
        wq_kernel<<<1, 256, 0, stream>>>(w, wsf, wbuf);
        conv_kernel<<<XN * 256, 256, 0, stream>>>(x, wbuf, wsf, bias, out);
    }
}